// Round 4
// baseline (702.525 us; speedup 1.0000x reference)
//
#include <hip/hip_runtime.h>

using bf16x8 = __attribute__((ext_vector_type(8))) __bf16;
using f32x4  = __attribute__((ext_vector_type(4))) float;

#define NE 1024

__device__ __forceinline__ unsigned short f2b(float f) {
    unsigned u = __builtin_bit_cast(unsigned, f);
    u = (u + 0x7FFFu + ((u >> 16) & 1u)) >> 16;
    return (unsigned short)u;
}

// C[M,N] = A[M,K] @ W[N,K]^T + bias, M=8192, N=K=1024, bf16 MFMA.
// ABF=0: A f32; ABF=1: A bf16 row-major.
// MODE 0: out bf16 row-major. MODE 1: out bf16 V^T [B=8][H=16][D=64][S=1024]. MODE 2: out f32.
template<int MODE, int ABF>
__global__ __launch_bounds__(256)
void proj_gemm(const void* __restrict__ Ap, const float* __restrict__ W,
               const float* __restrict__ bias, void* __restrict__ outp)
{
    __shared__ uint4 Al[1024];  // 128 rows x 64 bf16 (128B rows), XOR-swizzled
    __shared__ uint4 Bl[1024];
    const int tid  = threadIdx.x;
    const int lane = tid & 63;
    const int wid  = tid >> 6;
    const int wr = wid >> 1, wc = wid & 1;
    const int rowbase = blockIdx.x * 128;
    const int colbase = blockIdx.y * 128;
    f32x4 acc[4][4] = {};

    for (int kt = 0; kt < 16; ++kt) {
        __syncthreads();
        #pragma unroll
        for (int i = 0; i < 4; ++i) {
            int c = tid + i * 256;
            int row = c >> 3, colb = (c & 7) * 8;
            uint4 pa;
            if (ABF) {
                pa = *(const uint4*)((const unsigned short*)Ap + (size_t)(rowbase + row) * NE + kt * 64 + colb);
            } else {
                const float* ga = (const float*)Ap + (size_t)(rowbase + row) * NE + kt * 64 + colb;
                float4 a0 = *(const float4*)ga; float4 a1 = *(const float4*)(ga + 4);
                pa.x = f2b(a0.x) | ((unsigned)f2b(a0.y) << 16);
                pa.y = f2b(a0.z) | ((unsigned)f2b(a0.w) << 16);
                pa.z = f2b(a1.x) | ((unsigned)f2b(a1.y) << 16);
                pa.w = f2b(a1.z) | ((unsigned)f2b(a1.w) << 16);
            }
            const float* gb = W + (size_t)(colbase + row) * NE + kt * 64 + colb;
            float4 b0 = *(const float4*)gb; float4 b1 = *(const float4*)(gb + 4);
            uint4 pb;
            pb.x = f2b(b0.x) | ((unsigned)f2b(b0.y) << 16);
            pb.y = f2b(b0.z) | ((unsigned)f2b(b0.w) << 16);
            pb.z = f2b(b1.x) | ((unsigned)f2b(b1.y) << 16);
            pb.w = f2b(b1.z) | ((unsigned)f2b(b1.w) << 16);
            int ad = (row * 128 + colb * 2) ^ ((row & 7) << 4);
            Al[ad >> 4] = pa;
            Bl[ad >> 4] = pb;
        }
        __syncthreads();
        #pragma unroll
        for (int ks = 0; ks < 2; ++ks) {
            const int kb = ks * 64 + (lane >> 4) * 16;
            bf16x8 af[4], bf[4];
            #pragma unroll
            for (int m = 0; m < 4; ++m) {
                int row = wr * 64 + m * 16 + (lane & 15);
                af[m] = *(const bf16x8*)&Al[((row * 128 + kb) ^ ((row & 7) << 4)) >> 4];
            }
            #pragma unroll
            for (int n = 0; n < 4; ++n) {
                int row = wc * 64 + n * 16 + (lane & 15);
                bf[n] = *(const bf16x8*)&Bl[((row * 128 + kb) ^ ((row & 7) << 4)) >> 4];
            }
            #pragma unroll
            for (int m = 0; m < 4; ++m)
                #pragma unroll
                for (int n = 0; n < 4; ++n)
                    acc[m][n] = __builtin_amdgcn_mfma_f32_16x16x32_bf16(af[m], bf[n], acc[m][n], 0, 0, 0);
        }
    }

    #pragma unroll
    for (int m = 0; m < 4; ++m) {
        #pragma unroll
        for (int n = 0; n < 4; ++n) {
            int col = colbase + wc * 64 + n * 16 + (lane & 15);
            float bv = bias[col];
            #pragma unroll
            for (int r = 0; r < 4; ++r) {
                int row = rowbase + wr * 64 + m * 16 + (lane >> 4) * 4 + r;
                float v = acc[m][n][r] + bv;
                if (MODE == 0) {
                    ((unsigned short*)outp)[(size_t)row * NE + col] = f2b(v);
                } else if (MODE == 1) {
                    int b = row >> 10, s = row & 1023, h = col >> 6, d = col & 63;
                    ((unsigned short*)outp)[((size_t)((b * 16 + h) * 64 + d) << 10) + s] = f2b(v);
                } else {
                    ((float*)outp)[(size_t)row * NE + col] = v;
                }
            }
        }
    }
}

// S-pass: per (qt, kt, bh): E[q][k] = exp(QK^T/8 - 8)  (UNNORMALIZED, constant shift
// -> no reductions, no axis dependence). Q,K bf16 [8192][1024], head slice h*64.
__global__ __launch_bounds__(256)
void sexp_kernel(const unsigned short* __restrict__ Q, const unsigned short* __restrict__ K,
                 float* __restrict__ attn)
{
    __shared__ uint4 Al[1024];  // 128 q-rows x 64 d (128B)
    __shared__ uint4 Bl[1024];  // 128 k-rows x 64 d
    const int tid  = threadIdx.x;
    const int lane = tid & 63;
    const int wid  = tid >> 6;
    const int wr = wid >> 1, wc = wid & 1;
    const int qt = blockIdx.x >> 3, kt = blockIdx.x & 7;
    const int bh = blockIdx.y;
    const int b = bh >> 4, h = bh & 15;
    const unsigned short* Ag = Q + (size_t)(b * 1024 + qt * 128) * 1024 + h * 64;
    const unsigned short* Bg = K + (size_t)(b * 1024 + kt * 128) * 1024 + h * 64;

    #pragma unroll
    for (int i = 0; i < 4; ++i) {
        int c = tid + i * 256;
        int row = c >> 3, colb = (c & 7) * 8;
        uint4 pa = *(const uint4*)(Ag + (size_t)row * 1024 + colb);
        uint4 pb = *(const uint4*)(Bg + (size_t)row * 1024 + colb);
        int ad = (row * 128 + colb * 2) ^ ((row & 7) << 4);
        Al[ad >> 4] = pa;
        Bl[ad >> 4] = pb;
    }
    __syncthreads();

    f32x4 acc[4][4] = {};
    #pragma unroll
    for (int ks = 0; ks < 2; ++ks) {
        const int kb = ks * 64 + (lane >> 4) * 16;  // byte offset within 128B row (d-dim)
        bf16x8 af[4], bf[4];
        #pragma unroll
        for (int m = 0; m < 4; ++m) {
            int row = wr * 64 + m * 16 + (lane & 15);
            af[m] = *(const bf16x8*)&Al[((row * 128 + kb) ^ ((row & 7) << 4)) >> 4];
        }
        #pragma unroll
        for (int n = 0; n < 4; ++n) {
            int row = wc * 64 + n * 16 + (lane & 15);
            bf[n] = *(const bf16x8*)&Bl[((row * 128 + kb) ^ ((row & 7) << 4)) >> 4];
        }
        #pragma unroll
        for (int m = 0; m < 4; ++m)
            #pragma unroll
            for (int n = 0; n < 4; ++n)
                acc[m][n] = __builtin_amdgcn_mfma_f32_16x16x32_bf16(af[m], bf[n], acc[m][n], 0, 0, 0);
    }

    float* attnb = attn + ((size_t)bh * 1024 + qt * 128) * 1024 + kt * 128;
    #pragma unroll
    for (int m = 0; m < 4; ++m)
        #pragma unroll
        for (int n = 0; n < 4; ++n) {
            int col = wc * 64 + n * 16 + (lane & 15);
            #pragma unroll
            for (int r = 0; r < 4; ++r) {
                int row = wr * 64 + m * 16 + (lane >> 4) * 4 + r;
                attnb[(size_t)row * 1024 + col] = __expf(acc[m][n][r] * 0.125f - 8.0f);
            }
        }
}

// Row-normalize attn in place: one wave per row of 1024 f32.
__global__ __launch_bounds__(256)
void norm_kernel(float* __restrict__ attn)
{
    const int lane = threadIdx.x & 63;
    const int wid  = threadIdx.x >> 6;
    const size_t row = (size_t)blockIdx.x * 4 + wid;
    float4* R = (float4*)(attn + row * 1024);
    float s = 0.f;
    float4 v[4];
    #pragma unroll
    for (int i = 0; i < 4; ++i) {
        v[i] = R[i * 64 + lane];
        s += v[i].x + v[i].y + v[i].z + v[i].w;
    }
    #pragma unroll
    for (int off = 1; off <= 32; off <<= 1) s += __shfl_xor(s, off);
    float inv = 1.f / s;
    #pragma unroll
    for (int i = 0; i < 4; ++i) {
        v[i].x *= inv; v[i].y *= inv; v[i].z *= inv; v[i].w *= inv;
        R[i * 64 + lane] = v[i];
    }
}

// PV GEMM: per (qt, bh): O[q][d] = P[q][k] @ V^T[d][k]^T. P f32 (convert inline), VT bf16.
// O bf16 written into Og ([8192][1024] row-major, col = h*64+d).
__global__ __launch_bounds__(256)
void pv_kernel(const float* __restrict__ P, const unsigned short* __restrict__ VT,
               unsigned short* __restrict__ Og)
{
    __shared__ uint4 Al[1024];  // 128 q x 64 k bf16
    __shared__ uint4 Bl[512];   // 64 d x 64 k bf16
    const int tid  = threadIdx.x;
    const int lane = tid & 63;
    const int w    = tid >> 6;
    const int qt = blockIdx.x;
    const int bh = blockIdx.y;
    const int b = bh >> 4, h = bh & 15;
    const float* Ap = P + ((size_t)bh * 1024 + qt * 128) * 1024;
    const unsigned short* Bp = VT + (size_t)bh * 64 * 1024;

    f32x4 acc[2][4] = {};
    for (int kt = 0; kt < 16; ++kt) {
        __syncthreads();
        #pragma unroll
        for (int i = 0; i < 4; ++i) {
            int c = tid + i * 256;
            int row = c >> 3, colb = (c & 7) * 8;
            const float* ga = Ap + (size_t)row * 1024 + kt * 64 + colb;
            float4 a0 = *(const float4*)ga; float4 a1 = *(const float4*)(ga + 4);
            uint4 pa;
            pa.x = f2b(a0.x) | ((unsigned)f2b(a0.y) << 16);
            pa.y = f2b(a0.z) | ((unsigned)f2b(a0.w) << 16);
            pa.z = f2b(a1.x) | ((unsigned)f2b(a1.y) << 16);
            pa.w = f2b(a1.z) | ((unsigned)f2b(a1.w) << 16);
            Al[((row * 128 + colb * 2) ^ ((row & 7) << 4)) >> 4] = pa;
        }
        #pragma unroll
        for (int i = 0; i < 2; ++i) {
            int c = tid + i * 256;
            int row = c >> 3, colb = (c & 7) * 8;
            uint4 pb = *(const uint4*)(Bp + (size_t)row * 1024 + kt * 64 + colb);
            Bl[((row * 128 + colb * 2) ^ ((row & 7) << 4)) >> 4] = pb;
        }
        __syncthreads();
        #pragma unroll
        for (int ks = 0; ks < 2; ++ks) {
            const int kb = ks * 64 + (lane >> 4) * 16;
            bf16x8 af[2], bf[4];
            #pragma unroll
            for (int m = 0; m < 2; ++m) {
                int row = w * 32 + m * 16 + (lane & 15);
                af[m] = *(const bf16x8*)&Al[((row * 128 + kb) ^ ((row & 7) << 4)) >> 4];
            }
            #pragma unroll
            for (int n = 0; n < 4; ++n) {
                int row = n * 16 + (lane & 15);
                bf[n] = *(const bf16x8*)&Bl[((row * 128 + kb) ^ ((row & 7) << 4)) >> 4];
            }
            #pragma unroll
            for (int m = 0; m < 2; ++m)
                #pragma unroll
                for (int n = 0; n < 4; ++n)
                    acc[m][n] = __builtin_amdgcn_mfma_f32_16x16x32_bf16(af[m], bf[n], acc[m][n], 0, 0, 0);
        }
    }

    #pragma unroll
    for (int m = 0; m < 2; ++m)
        #pragma unroll
        for (int n = 0; n < 4; ++n) {
            int col = h * 64 + n * 16 + (lane & 15);
            #pragma unroll
            for (int r = 0; r < 4; ++r) {
                int row = b * 1024 + qt * 128 + w * 32 + m * 16 + (lane >> 4) * 4 + r;
                Og[(size_t)row * 1024 + col] = f2b(acc[m][n][r]);
            }
        }
}

extern "C" void kernel_launch(void* const* d_in, const int* in_sizes, int n_in,
                              void* d_out, int out_size, void* d_ws, size_t ws_size,
                              hipStream_t stream) {
    (void)in_sizes; (void)n_in; (void)out_size; (void)ws_size;
    const float* q    = (const float*)d_in[0];
    const float* Wq_w = (const float*)d_in[1];
    const float* Wq_b = (const float*)d_in[2];
    const float* Wk_w = (const float*)d_in[3];
    const float* Wk_b = (const float*)d_in[4];
    const float* Wv_w = (const float*)d_in[5];
    const float* Wv_b = (const float*)d_in[6];
    const float* Wo_w = (const float*)d_in[7];
    const float* Wo_b = (const float*)d_in[8];

    char* ws = (char*)d_ws;                         // total ws use: 48 MiB
    unsigned short* Qws  = (unsigned short*)(ws);             // Q bf16, later O bf16
    unsigned short* Kws  = (unsigned short*)(ws + (16u << 20));
    unsigned short* VTws = (unsigned short*)(ws + (32u << 20));

    float* outp  = (float*)d_out;                   // f32 out [8,1024,1024]
    float* attnp = outp + 8388608;                  // f32 attn [8,16,1024,1024]

    dim3 blk(256);
    dim3 gproj(64, 8);
    proj_gemm<0, 0><<<gproj, blk, 0, stream>>>(q, Wq_w, Wq_b, Qws);
    proj_gemm<0, 0><<<gproj, blk, 0, stream>>>(q, Wk_w, Wk_b, Kws);
    proj_gemm<1, 0><<<gproj, blk, 0, stream>>>(q, Wv_w, Wv_b, VTws);
    sexp_kernel<<<dim3(64, 128), blk, 0, stream>>>(Qws, Kws, attnp);
    norm_kernel<<<dim3(32768), blk, 0, stream>>>(attnp);
    pv_kernel<<<dim3(8, 128), blk, 0, stream>>>(attnp, VTws, Qws);
    proj_gemm<2, 1><<<gproj, blk, 0, stream>>>(Qws, Wo_w, Wo_b, outp);
}

// Round 5
// 421.993 us; speedup vs baseline: 1.6648x; 1.6648x over previous
//
#include <hip/hip_runtime.h>

using bf16x8 = __attribute__((ext_vector_type(8))) __bf16;
using f32x4  = __attribute__((ext_vector_type(4))) float;

#define NE 1024

__device__ __forceinline__ unsigned short f2b(float f) {
    unsigned u = __builtin_bit_cast(unsigned, f);
    u = (u + 0x7FFFu + ((u >> 16) & 1u)) >> 16;
    return (unsigned short)u;
}

// C[M,N] = A[M,K] @ W[N,K]^T + bias, M=8192, N=K=1024, bf16 MFMA.
// ABF=0: A f32; ABF=1: A bf16 row-major.
// MODE 0: out bf16 row-major. MODE 1: out bf16 V^T [B=8][H=16][D=64][S=1024]. MODE 2: out f32.
template<int MODE, int ABF>
__global__ __launch_bounds__(256)
void proj_gemm(const void* __restrict__ Ap, const float* __restrict__ W,
               const float* __restrict__ bias, void* __restrict__ outp)
{
    __shared__ uint4 Al[1024];  // 128 rows x 64 bf16 (128B rows), XOR-swizzled
    __shared__ uint4 Bl[1024];
    const int tid  = threadIdx.x;
    const int lane = tid & 63;
    const int wid  = tid >> 6;
    const int wr = wid >> 1, wc = wid & 1;
    const int rowbase = blockIdx.x * 128;
    const int colbase = blockIdx.y * 128;
    f32x4 acc[4][4] = {};

    for (int kt = 0; kt < 16; ++kt) {
        __syncthreads();
        #pragma unroll
        for (int i = 0; i < 4; ++i) {
            int c = tid + i * 256;
            int row = c >> 3, colb = (c & 7) * 8;
            uint4 pa;
            if (ABF) {
                pa = *(const uint4*)((const unsigned short*)Ap + (size_t)(rowbase + row) * NE + kt * 64 + colb);
            } else {
                const float* ga = (const float*)Ap + (size_t)(rowbase + row) * NE + kt * 64 + colb;
                float4 a0 = *(const float4*)ga; float4 a1 = *(const float4*)(ga + 4);
                pa.x = f2b(a0.x) | ((unsigned)f2b(a0.y) << 16);
                pa.y = f2b(a0.z) | ((unsigned)f2b(a0.w) << 16);
                pa.z = f2b(a1.x) | ((unsigned)f2b(a1.y) << 16);
                pa.w = f2b(a1.z) | ((unsigned)f2b(a1.w) << 16);
            }
            const float* gb = W + (size_t)(colbase + row) * NE + kt * 64 + colb;
            float4 b0 = *(const float4*)gb; float4 b1 = *(const float4*)(gb + 4);
            uint4 pb;
            pb.x = f2b(b0.x) | ((unsigned)f2b(b0.y) << 16);
            pb.y = f2b(b0.z) | ((unsigned)f2b(b0.w) << 16);
            pb.z = f2b(b1.x) | ((unsigned)f2b(b1.y) << 16);
            pb.w = f2b(b1.z) | ((unsigned)f2b(b1.w) << 16);
            int ad = (row * 128 + colb * 2) ^ ((row & 7) << 4);
            Al[ad >> 4] = pa;
            Bl[ad >> 4] = pb;
        }
        __syncthreads();
        #pragma unroll
        for (int ks = 0; ks < 2; ++ks) {
            const int kb = ks * 64 + (lane >> 4) * 16;
            bf16x8 af[4], bf[4];
            #pragma unroll
            for (int m = 0; m < 4; ++m) {
                int row = wr * 64 + m * 16 + (lane & 15);
                af[m] = *(const bf16x8*)&Al[((row * 128 + kb) ^ ((row & 7) << 4)) >> 4];
            }
            #pragma unroll
            for (int n = 0; n < 4; ++n) {
                int row = wc * 64 + n * 16 + (lane & 15);
                bf[n] = *(const bf16x8*)&Bl[((row * 128 + kb) ^ ((row & 7) << 4)) >> 4];
            }
            #pragma unroll
            for (int m = 0; m < 4; ++m)
                #pragma unroll
                for (int n = 0; n < 4; ++n)
                    acc[m][n] = __builtin_amdgcn_mfma_f32_16x16x32_bf16(af[m], bf[n], acc[m][n], 0, 0, 0);
        }
    }

    #pragma unroll
    for (int m = 0; m < 4; ++m) {
        #pragma unroll
        for (int n = 0; n < 4; ++n) {
            int col = colbase + wc * 64 + n * 16 + (lane & 15);
            float bv = bias[col];
            #pragma unroll
            for (int r = 0; r < 4; ++r) {
                int row = rowbase + wr * 64 + m * 16 + (lane >> 4) * 4 + r;
                float v = acc[m][n][r] + bv;
                if (MODE == 0) {
                    ((unsigned short*)outp)[(size_t)row * NE + col] = f2b(v);
                } else if (MODE == 1) {
                    int b = row >> 10, s = row & 1023, h = col >> 6, d = col & 63;
                    ((unsigned short*)outp)[((size_t)((b * 16 + h) * 64 + d) << 10) + s] = f2b(v);
                } else {
                    ((float*)outp)[(size_t)row * NE + col] = v;
                }
            }
        }
    }
}

// Fused attention: per block (qt: 128 q-rows, bh). Two loops over kt (128-k tiles):
// loop1 computes rowsum of E=exp(QK^T/8-8); loop2 recomputes S, writes normalized
// attn (f32, float4), packs P bf16 to LDS, accumulates PV from global V^T.
// S via swapped mfma(K,Q) -> D[k][q]: register quad = 4 consecutive k.
__global__ __launch_bounds__(256)
void fused_attn(const unsigned short* __restrict__ Q,
                const unsigned short* __restrict__ K,
                const unsigned short* __restrict__ VT,
                float* __restrict__ attn, unsigned short* __restrict__ Og)
{
    __shared__ uint4 Ql[1024];   // 128 q x 64 d bf16 (128B rows), swizzled
    __shared__ uint4 Kl[1024];   // 128 k x 64 d bf16
    __shared__ uint4 Pl[2048];   // 128 q x 128 k bf16 (256B rows), swizzled
    __shared__ float rs4[4][128];
    __shared__ float il[128];
    const int tid  = threadIdx.x;
    const int lane = tid & 63;
    const int w    = tid >> 6;
    const int qt = blockIdx.x;
    const int bh = blockIdx.y;
    const int b = bh >> 4, h = bh & 15;
    const unsigned short* Qg = Q  + (size_t)(b * 1024 + qt * 128) * 1024 + h * 64;
    const unsigned short* Kg = K  + (size_t)(b * 1024) * 1024 + h * 64;
    const unsigned short* Vg = VT + (size_t)bh * 64 * 1024;

    // stage Q tile once
    #pragma unroll
    for (int i = 0; i < 4; ++i) {
        int c = tid + i * 256;
        int row = c >> 3, colb = (c & 7) * 8;
        uint4 v = *(const uint4*)(Qg + (size_t)row * 1024 + colb);
        Ql[((row * 128 + colb * 2) ^ ((row & 7) << 4)) >> 4] = v;
    }

    // ---- loop 1: row sums ----
    float rs_p[8] = {0.f, 0.f, 0.f, 0.f, 0.f, 0.f, 0.f, 0.f};
    for (int kt = 0; kt < 8; ++kt) {
        __syncthreads();
        #pragma unroll
        for (int i = 0; i < 4; ++i) {
            int c = tid + i * 256;
            int row = c >> 3, colb = (c & 7) * 8;
            uint4 v = *(const uint4*)(Kg + (size_t)(kt * 128 + row) * 1024 + colb);
            Kl[((row * 128 + colb * 2) ^ ((row & 7) << 4)) >> 4] = v;
        }
        __syncthreads();
        f32x4 sa[2][8] = {};
        #pragma unroll
        for (int ks = 0; ks < 2; ++ks) {
            const int kb = ks * 64 + (lane >> 4) * 16;
            bf16x8 kf[2], qf[8];
            #pragma unroll
            for (int m = 0; m < 2; ++m) {
                int row = w * 32 + m * 16 + (lane & 15);
                kf[m] = *(const bf16x8*)&Kl[((row * 128 + kb) ^ ((row & 7) << 4)) >> 4];
            }
            #pragma unroll
            for (int n = 0; n < 8; ++n) {
                int row = n * 16 + (lane & 15);
                qf[n] = *(const bf16x8*)&Ql[((row * 128 + kb) ^ ((row & 7) << 4)) >> 4];
            }
            #pragma unroll
            for (int m = 0; m < 2; ++m)
                #pragma unroll
                for (int n = 0; n < 8; ++n)
                    sa[m][n] = __builtin_amdgcn_mfma_f32_16x16x32_bf16(kf[m], qf[n], sa[m][n], 0, 0, 0);
        }
        #pragma unroll
        for (int n = 0; n < 8; ++n)
            #pragma unroll
            for (int m = 0; m < 2; ++m)
                #pragma unroll
                for (int r = 0; r < 4; ++r)
                    rs_p[n] += __expf(sa[m][n][r] * 0.125f - 8.0f);
    }
    #pragma unroll
    for (int n = 0; n < 8; ++n) {
        rs_p[n] += __shfl_xor(rs_p[n], 16);
        rs_p[n] += __shfl_xor(rs_p[n], 32);
    }
    if (lane < 16) {
        #pragma unroll
        for (int n = 0; n < 8; ++n) rs4[w][n * 16 + lane] = rs_p[n];
    }
    __syncthreads();
    if (tid < 128) il[tid] = 1.0f / (rs4[0][tid] + rs4[1][tid] + rs4[2][tid] + rs4[3][tid]);

    // ---- loop 2: normalized attn write + PV ----
    f32x4 oa[2][4] = {};
    float* attnq = attn + ((size_t)bh * 1024 + qt * 128) * 1024;
    for (int kt = 0; kt < 8; ++kt) {
        __syncthreads();
        #pragma unroll
        for (int i = 0; i < 4; ++i) {
            int c = tid + i * 256;
            int row = c >> 3, colb = (c & 7) * 8;
            uint4 v = *(const uint4*)(Kg + (size_t)(kt * 128 + row) * 1024 + colb);
            Kl[((row * 128 + colb * 2) ^ ((row & 7) << 4)) >> 4] = v;
        }
        __syncthreads();
        f32x4 sa[2][8] = {};
        #pragma unroll
        for (int ks = 0; ks < 2; ++ks) {
            const int kb = ks * 64 + (lane >> 4) * 16;
            bf16x8 kf[2], qf[8];
            #pragma unroll
            for (int m = 0; m < 2; ++m) {
                int row = w * 32 + m * 16 + (lane & 15);
                kf[m] = *(const bf16x8*)&Kl[((row * 128 + kb) ^ ((row & 7) << 4)) >> 4];
            }
            #pragma unroll
            for (int n = 0; n < 8; ++n) {
                int row = n * 16 + (lane & 15);
                qf[n] = *(const bf16x8*)&Ql[((row * 128 + kb) ^ ((row & 7) << 4)) >> 4];
            }
            #pragma unroll
            for (int m = 0; m < 2; ++m)
                #pragma unroll
                for (int n = 0; n < 8; ++n)
                    sa[m][n] = __builtin_amdgcn_mfma_f32_16x16x32_bf16(kf[m], qf[n], sa[m][n], 0, 0, 0);
        }
        // normalize, write attn tile [q][kt*128 + k], pack P into Pl
        #pragma unroll
        for (int n = 0; n < 8; ++n) {
            int q = n * 16 + (lane & 15);
            float iv = il[q];
            #pragma unroll
            for (int m = 0; m < 2; ++m) {
                int k0 = w * 32 + m * 16 + (lane >> 4) * 4;
                float4 p4;
                p4.x = __expf(sa[m][n][0] * 0.125f - 8.0f) * iv;
                p4.y = __expf(sa[m][n][1] * 0.125f - 8.0f) * iv;
                p4.z = __expf(sa[m][n][2] * 0.125f - 8.0f) * iv;
                p4.w = __expf(sa[m][n][3] * 0.125f - 8.0f) * iv;
                *(float4*)(attnq + (size_t)q * 1024 + kt * 128 + k0) = p4;
                uint2 pk;
                pk.x = f2b(p4.x) | ((unsigned)f2b(p4.y) << 16);
                pk.y = f2b(p4.z) | ((unsigned)f2b(p4.w) << 16);
                int ad = (q * 256 + k0 * 2) ^ ((q & 7) << 4);
                *(uint2*)((char*)Pl + ad) = pk;
            }
        }
        __syncthreads();
        // PV: A = P rows (q), B = V^T rows (d) from global, K-dim = this kt's 128
        #pragma unroll
        for (int ks = 0; ks < 4; ++ks) {
            const int kb = ks * 64 + (lane >> 4) * 16;  // byte offset in 256B P row
            bf16x8 pa[2], vb[4];
            #pragma unroll
            for (int m2 = 0; m2 < 2; ++m2) {
                int row = w * 32 + m2 * 16 + (lane & 15);
                pa[m2] = *(const bf16x8*)((const char*)Pl + ((row * 256 + kb) ^ ((row & 7) << 4)));
            }
            #pragma unroll
            for (int n2 = 0; n2 < 4; ++n2) {
                int d = n2 * 16 + (lane & 15);
                vb[n2] = *(const bf16x8*)(Vg + (size_t)d * 1024 + kt * 128 + ks * 32 + (lane >> 4) * 8);
            }
            #pragma unroll
            for (int m2 = 0; m2 < 2; ++m2)
                #pragma unroll
                for (int n2 = 0; n2 < 4; ++n2)
                    oa[m2][n2] = __builtin_amdgcn_mfma_f32_16x16x32_bf16(pa[m2], vb[n2], oa[m2][n2], 0, 0, 0);
        }
    }
    // O write (bf16) into Og rows [b*1024+qt*128 ..], cols [h*64 ..]
    unsigned short* Ob = Og + (size_t)(b * 1024 + qt * 128) * 1024 + h * 64;
    #pragma unroll
    for (int m2 = 0; m2 < 2; ++m2)
        #pragma unroll
        for (int n2 = 0; n2 < 4; ++n2) {
            int d = n2 * 16 + (lane & 15);
            #pragma unroll
            for (int r = 0; r < 4; ++r) {
                int qrow = w * 32 + m2 * 16 + (lane >> 4) * 4 + r;
                Ob[(size_t)qrow * 1024 + d] = f2b(oa[m2][n2][r]);
            }
        }
}

extern "C" void kernel_launch(void* const* d_in, const int* in_sizes, int n_in,
                              void* d_out, int out_size, void* d_ws, size_t ws_size,
                              hipStream_t stream) {
    (void)in_sizes; (void)n_in; (void)out_size; (void)ws_size;
    const float* q    = (const float*)d_in[0];
    const float* Wq_w = (const float*)d_in[1];
    const float* Wq_b = (const float*)d_in[2];
    const float* Wk_w = (const float*)d_in[3];
    const float* Wk_b = (const float*)d_in[4];
    const float* Wv_w = (const float*)d_in[5];
    const float* Wv_b = (const float*)d_in[6];
    const float* Wo_w = (const float*)d_in[7];
    const float* Wo_b = (const float*)d_in[8];

    char* ws = (char*)d_ws;                         // total ws use: 48 MiB
    unsigned short* Qws  = (unsigned short*)(ws);             // Q bf16, later O bf16
    unsigned short* Kws  = (unsigned short*)(ws + (16u << 20));
    unsigned short* VTws = (unsigned short*)(ws + (32u << 20));

    float* outp  = (float*)d_out;                   // f32 out [8,1024,1024]
    float* attnp = outp + 8388608;                  // f32 attn [8,16,1024,1024]

    dim3 blk(256);
    dim3 gproj(64, 8);
    proj_gemm<0, 0><<<gproj, blk, 0, stream>>>(q, Wq_w, Wq_b, Qws);
    proj_gemm<0, 0><<<gproj, blk, 0, stream>>>(q, Wk_w, Wk_b, Kws);
    proj_gemm<1, 0><<<gproj, blk, 0, stream>>>(q, Wv_w, Wv_b, VTws);
    fused_attn<<<dim3(8, 128), blk, 0, stream>>>(Qws, Kws, VTws, attnp, Qws);
    proj_gemm<2, 1><<<gproj, blk, 0, stream>>>(Qws, Wo_w, Wo_b, outp);
}

// Round 6
// 338.256 us; speedup vs baseline: 2.0769x; 1.2476x over previous
//
#include <hip/hip_runtime.h>

using bf16x8 = __attribute__((ext_vector_type(8))) __bf16;
using f32x4  = __attribute__((ext_vector_type(4))) float;

#define NE 1024

__device__ __forceinline__ unsigned short f2b(float f) {
    unsigned u = __builtin_bit_cast(unsigned, f);
    u = (u + 0x7FFFu + ((u >> 16) & 1u)) >> 16;
    return (unsigned short)u;
}

typedef __attribute__((address_space(1))) const void gvoid_t;
typedef __attribute__((address_space(3))) void lvoid_t;

// Stage a 128-row x 128-byte (64 bf16) tile into 16KB LDS via global_load_lds,
// source pre-swizzled so that LDS content satisfies:
//   lds[row*128 + (x ^ ((row&7)<<4))] = g[row][x]   (read with same XOR).
// gbase: element ptr to tile origin; rowstride in bf16 elems.
__device__ __forceinline__ void stage128(const unsigned short* gbase, char* lds, int tid)
{
    const int w = tid >> 6, l = tid & 63;
    #pragma unroll
    for (int i = 0; i < 4; ++i) {
        int grp = i * 4 + w;                 // 8-row group 0..15
        int row = grp * 8 + (l >> 3);
        int srcb = ((l & 7) * 16) ^ ((l >> 3) << 4);
        const char* g = (const char*)(gbase + (size_t)row * NE) + srcb;
        char* d = lds + grp * 1024;          // wave-uniform base; HW adds lane*16
        __builtin_amdgcn_global_load_lds((gvoid_t*)g, (lvoid_t*)d, 16, 0, 0);
    }
}

// f32 -> bf16 (RNE), 8 elems/thread, exact-size launch.
__global__ __launch_bounds__(256)
void conv_bf16(const float* __restrict__ src, unsigned short* __restrict__ dst)
{
    size_t i = ((size_t)blockIdx.x * 256 + threadIdx.x) * 8;
    float4 a0 = *(const float4*)(src + i);
    float4 a1 = *(const float4*)(src + i + 4);
    uint4 p;
    p.x = f2b(a0.x) | ((unsigned)f2b(a0.y) << 16);
    p.y = f2b(a0.z) | ((unsigned)f2b(a0.w) << 16);
    p.z = f2b(a1.x) | ((unsigned)f2b(a1.y) << 16);
    p.w = f2b(a1.z) | ((unsigned)f2b(a1.w) << 16);
    *(uint4*)(dst + i) = p;
}

// C[M,N] = A[M,K] @ W[N,K]^T + bias; A,W bf16; M=8192, N=K=1024.
// grid 512 linear, XCD-swizzled: XCD c gets rowblocks [8c,8c+8) x all colblocks.
// MODE 0: out bf16 row-major. MODE 1: out bf16 V^T [B][H][D=64][S]. MODE 2: f32.
template<int MODE>
__global__ __launch_bounds__(256)
void proj_bt(const unsigned short* __restrict__ A, const unsigned short* __restrict__ W,
             const float* __restrict__ bias, void* __restrict__ outp)
{
    __shared__ char Asm[16384], Bsm[16384];
    const int tid  = threadIdx.x;
    const int lane = tid & 63;
    const int wid  = tid >> 6;
    const int wr = wid >> 1, wc = wid & 1;
    const int swz = (blockIdx.x & 7) * 64 + (blockIdx.x >> 3);
    const int rowbase = (swz >> 3) * 128;
    const int colbase = (swz & 7) * 128;
    f32x4 acc[4][4] = {};

    for (int kt = 0; kt < 16; ++kt) {
        __syncthreads();
        stage128(A + (size_t)rowbase * NE + kt * 64, Asm, tid);
        stage128(W + (size_t)colbase * NE + kt * 64, Bsm, tid);
        __syncthreads();   // compiler drains vmcnt(0) before barrier -> LDS ready
        #pragma unroll
        for (int ks = 0; ks < 2; ++ks) {
            const int kb = ks * 64 + (lane >> 4) * 16;
            bf16x8 af[4], bf[4];
            #pragma unroll
            for (int m = 0; m < 4; ++m) {
                int row = wr * 64 + m * 16 + (lane & 15);
                af[m] = *(const bf16x8*)(Asm + ((row * 128 + kb) ^ ((row & 7) << 4)));
            }
            #pragma unroll
            for (int n = 0; n < 4; ++n) {
                int row = wc * 64 + n * 16 + (lane & 15);
                bf[n] = *(const bf16x8*)(Bsm + ((row * 128 + kb) ^ ((row & 7) << 4)));
            }
            #pragma unroll
            for (int m = 0; m < 4; ++m)
                #pragma unroll
                for (int n = 0; n < 4; ++n)
                    acc[m][n] = __builtin_amdgcn_mfma_f32_16x16x32_bf16(af[m], bf[n], acc[m][n], 0, 0, 0);
        }
    }

    #pragma unroll
    for (int m = 0; m < 4; ++m) {
        #pragma unroll
        for (int n = 0; n < 4; ++n) {
            int col = colbase + wc * 64 + n * 16 + (lane & 15);
            float bv = bias[col];
            #pragma unroll
            for (int r = 0; r < 4; ++r) {
                int row = rowbase + wr * 64 + m * 16 + (lane >> 4) * 4 + r;
                float v = acc[m][n][r] + bv;
                if (MODE == 0) {
                    ((unsigned short*)outp)[(size_t)row * NE + col] = f2b(v);
                } else if (MODE == 1) {
                    int b = row >> 10, s = row & 1023, h = col >> 6, d = col & 63;
                    ((unsigned short*)outp)[((size_t)((b * 16 + h) * 64 + d) << 10) + s] = f2b(v);
                } else {
                    ((float*)outp)[(size_t)row * NE + col] = v;
                }
            }
        }
    }
}

// Fused attention. grid 1024 linear, XCD-swizzled so each XCD owns 16 bh
// (K/V L2-resident). Per block: 128 q-rows of one (b,h).
// Loop1: rowsum of E=exp(QK^T/8-8); Loop2: recompute, write normalized attn f32,
// pack P bf16 to LDS, accumulate PV from global V^T. S via swapped mfma(K,Q).
__global__ __launch_bounds__(256)
void fused_attn(const unsigned short* __restrict__ Q,
                const unsigned short* __restrict__ K,
                const unsigned short* __restrict__ VT,
                float* __restrict__ attn, unsigned short* __restrict__ Og)
{
    __shared__ char Qsm[16384], Ksm[16384];
    __shared__ char Psm[32768];          // 128 q x 256B rows, swizzled
    __shared__ float rs4[4][128];
    __shared__ float il[128];
    const int tid  = threadIdx.x;
    const int lane = tid & 63;
    const int w    = tid >> 6;
    const int swzb = (blockIdx.x & 7) * 128 + (blockIdx.x >> 3);
    const int bh = swzb >> 3, qt = swzb & 7;
    const int b = bh >> 4, h = bh & 15;
    const unsigned short* Qg = Q  + (size_t)(b * 1024 + qt * 128) * 1024 + h * 64;
    const unsigned short* Kg = K  + (size_t)(b * 1024) * 1024 + h * 64;
    const unsigned short* Vg = VT + (size_t)bh * 64 * 1024;

    stage128(Qg, Qsm, tid);   // drained by first barrier below

    // ---- loop 1: row sums ----
    float rs_p[8] = {0.f, 0.f, 0.f, 0.f, 0.f, 0.f, 0.f, 0.f};
    for (int kt = 0; kt < 8; ++kt) {
        __syncthreads();
        stage128(Kg + (size_t)(kt * 128) * 1024, Ksm, tid);
        __syncthreads();
        f32x4 sa[2][8] = {};
        #pragma unroll
        for (int ks = 0; ks < 2; ++ks) {
            const int kb = ks * 64 + (lane >> 4) * 16;
            bf16x8 kf[2], qf[8];
            #pragma unroll
            for (int m = 0; m < 2; ++m) {
                int row = w * 32 + m * 16 + (lane & 15);
                kf[m] = *(const bf16x8*)(Ksm + ((row * 128 + kb) ^ ((row & 7) << 4)));
            }
            #pragma unroll
            for (int n = 0; n < 8; ++n) {
                int row = n * 16 + (lane & 15);
                qf[n] = *(const bf16x8*)(Qsm + ((row * 128 + kb) ^ ((row & 7) << 4)));
            }
            #pragma unroll
            for (int m = 0; m < 2; ++m)
                #pragma unroll
                for (int n = 0; n < 8; ++n)
                    sa[m][n] = __builtin_amdgcn_mfma_f32_16x16x32_bf16(kf[m], qf[n], sa[m][n], 0, 0, 0);
        }
        #pragma unroll
        for (int n = 0; n < 8; ++n)
            #pragma unroll
            for (int m = 0; m < 2; ++m)
                #pragma unroll
                for (int r = 0; r < 4; ++r)
                    rs_p[n] += __expf(sa[m][n][r] * 0.125f - 8.0f);
    }
    #pragma unroll
    for (int n = 0; n < 8; ++n) {
        rs_p[n] += __shfl_xor(rs_p[n], 16);
        rs_p[n] += __shfl_xor(rs_p[n], 32);
    }
    if (lane < 16) {
        #pragma unroll
        for (int n = 0; n < 8; ++n) rs4[w][n * 16 + lane] = rs_p[n];
    }
    __syncthreads();
    if (tid < 128) il[tid] = 1.0f / (rs4[0][tid] + rs4[1][tid] + rs4[2][tid] + rs4[3][tid]);

    // ---- loop 2: normalized attn write + PV ----
    f32x4 oa[2][4] = {};
    float* attnq = attn + ((size_t)bh * 1024 + qt * 128) * 1024;
    for (int kt = 0; kt < 8; ++kt) {
        __syncthreads();
        stage128(Kg + (size_t)(kt * 128) * 1024, Ksm, tid);
        __syncthreads();
        f32x4 sa[2][8] = {};
        #pragma unroll
        for (int ks = 0; ks < 2; ++ks) {
            const int kb = ks * 64 + (lane >> 4) * 16;
            bf16x8 kf[2], qf[8];
            #pragma unroll
            for (int m = 0; m < 2; ++m) {
                int row = w * 32 + m * 16 + (lane & 15);
                kf[m] = *(const bf16x8*)(Ksm + ((row * 128 + kb) ^ ((row & 7) << 4)));
            }
            #pragma unroll
            for (int n = 0; n < 8; ++n) {
                int row = n * 16 + (lane & 15);
                qf[n] = *(const bf16x8*)(Qsm + ((row * 128 + kb) ^ ((row & 7) << 4)));
            }
            #pragma unroll
            for (int m = 0; m < 2; ++m)
                #pragma unroll
                for (int n = 0; n < 8; ++n)
                    sa[m][n] = __builtin_amdgcn_mfma_f32_16x16x32_bf16(kf[m], qf[n], sa[m][n], 0, 0, 0);
        }
        #pragma unroll
        for (int n = 0; n < 8; ++n) {
            int q = n * 16 + (lane & 15);
            float iv = il[q];
            #pragma unroll
            for (int m = 0; m < 2; ++m) {
                int k0 = w * 32 + m * 16 + (lane >> 4) * 4;
                float4 p4;
                p4.x = __expf(sa[m][n][0] * 0.125f - 8.0f) * iv;
                p4.y = __expf(sa[m][n][1] * 0.125f - 8.0f) * iv;
                p4.z = __expf(sa[m][n][2] * 0.125f - 8.0f) * iv;
                p4.w = __expf(sa[m][n][3] * 0.125f - 8.0f) * iv;
                *(float4*)(attnq + (size_t)q * 1024 + kt * 128 + k0) = p4;
                uint2 pk;
                pk.x = f2b(p4.x) | ((unsigned)f2b(p4.y) << 16);
                pk.y = f2b(p4.z) | ((unsigned)f2b(p4.w) << 16);
                int ad = (q * 256 + k0 * 2) ^ ((q & 7) << 4);
                *(uint2*)(Psm + ad) = pk;
            }
        }
        __syncthreads();
        #pragma unroll
        for (int ks = 0; ks < 4; ++ks) {
            const int kb = ks * 64 + (lane >> 4) * 16;   // byte off in 256B P row
            bf16x8 pa[2], vb[4];
            #pragma unroll
            for (int m2 = 0; m2 < 2; ++m2) {
                int row = w * 32 + m2 * 16 + (lane & 15);
                pa[m2] = *(const bf16x8*)(Psm + ((row * 256 + kb) ^ ((row & 7) << 4)));
            }
            #pragma unroll
            for (int n2 = 0; n2 < 4; ++n2) {
                int d = n2 * 16 + (lane & 15);
                vb[n2] = *(const bf16x8*)(Vg + (size_t)d * 1024 + kt * 128 + ks * 32 + (lane >> 4) * 8);
            }
            #pragma unroll
            for (int m2 = 0; m2 < 2; ++m2)
                #pragma unroll
                for (int n2 = 0; n2 < 4; ++n2)
                    oa[m2][n2] = __builtin_amdgcn_mfma_f32_16x16x32_bf16(pa[m2], vb[n2], oa[m2][n2], 0, 0, 0);
        }
    }
    unsigned short* Ob = Og + (size_t)(b * 1024 + qt * 128) * 1024 + h * 64;
    #pragma unroll
    for (int m2 = 0; m2 < 2; ++m2)
        #pragma unroll
        for (int n2 = 0; n2 < 4; ++n2) {
            int d = n2 * 16 + (lane & 15);
            #pragma unroll
            for (int r = 0; r < 4; ++r) {
                int qrow = w * 32 + m2 * 16 + (lane >> 4) * 4 + r;
                Ob[(size_t)qrow * 1024 + d] = f2b(oa[m2][n2][r]);
            }
        }
}

extern "C" void kernel_launch(void* const* d_in, const int* in_sizes, int n_in,
                              void* d_out, int out_size, void* d_ws, size_t ws_size,
                              hipStream_t stream) {
    (void)in_sizes; (void)n_in; (void)out_size; (void)ws_size;
    const float* q    = (const float*)d_in[0];
    const float* Wq_w = (const float*)d_in[1];
    const float* Wq_b = (const float*)d_in[2];
    const float* Wk_w = (const float*)d_in[3];
    const float* Wk_b = (const float*)d_in[4];
    const float* Wv_w = (const float*)d_in[5];
    const float* Wv_b = (const float*)d_in[6];
    const float* Wo_w = (const float*)d_in[7];
    const float* Wo_b = (const float*)d_in[8];

    char* ws = (char*)d_ws;                              // ws use: 48 MiB
    unsigned short* Qws  = (unsigned short*)(ws);        // Q bf16, later O bf16
    unsigned short* Kws  = (unsigned short*)(ws + (16u << 20));  // K bf16, later Wo bf16
    unsigned short* VTws = (unsigned short*)(ws + (32u << 20));

    float* outp  = (float*)d_out;                        // f32 out [8,1024,1024]
    float* attnp = outp + 8388608;                       // f32 attn [8,16,1024,1024]

    // bf16 scratch inside the attn region (free until fused_attn writes it)
    char* scr = (char*)attnp;
    unsigned short* qbf = (unsigned short*)scr;                    // 16 MiB
    unsigned short* wqb = (unsigned short*)(scr + (16u << 20));    // 2 MiB each
    unsigned short* wkb = (unsigned short*)(scr + (18u << 20));
    unsigned short* wvb = (unsigned short*)(scr + (20u << 20));

    dim3 blk(256);
    conv_bf16<<<dim3(4096), blk, 0, stream>>>(q, qbf);
    conv_bf16<<<dim3(512),  blk, 0, stream>>>(Wq_w, wqb);
    conv_bf16<<<dim3(512),  blk, 0, stream>>>(Wk_w, wkb);
    conv_bf16<<<dim3(512),  blk, 0, stream>>>(Wv_w, wvb);
    proj_bt<0><<<dim3(512), blk, 0, stream>>>(qbf, wqb, Wq_b, Qws);
    proj_bt<0><<<dim3(512), blk, 0, stream>>>(qbf, wkb, Wk_b, Kws);
    proj_bt<1><<<dim3(512), blk, 0, stream>>>(qbf, wvb, Wv_b, VTws);
    fused_attn<<<dim3(1024), blk, 0, stream>>>(Qws, Kws, VTws, attnp, Qws);
    conv_bf16<<<dim3(512),  blk, 0, stream>>>(Wo_w, Kws);          // Kws free now
    proj_bt<2><<<dim3(512), blk, 0, stream>>>(Qws, Kws, Wo_b, outp);
}

// Round 7
// 287.531 us; speedup vs baseline: 2.4433x; 1.1764x over previous
//
#include <hip/hip_runtime.h>

using bf16x8 = __attribute__((ext_vector_type(8))) __bf16;
using f32x4  = __attribute__((ext_vector_type(4))) float;

#define NE 1024
#define C1E 0.18033688011112042f   // 0.125 * log2(e)
#define C2E -11.541560327111707f   // -8 * log2(e)

__device__ __forceinline__ unsigned short f2b(float f) {
    unsigned u = __builtin_bit_cast(unsigned, f);
    u = (u + 0x7FFFu + ((u >> 16) & 1u)) >> 16;
    return (unsigned short)u;
}

typedef __attribute__((address_space(1))) const void gvoid_t;
typedef __attribute__((address_space(3))) void lvoid_t;

// Stage a 128-row x 128B (64 bf16) tile into 16KB LDS via global_load_lds,
// source pre-swizzled so lds[row*128 + (x ^ ((row&7)<<4))] = g[row][x].
__device__ __forceinline__ void stage128(const unsigned short* gbase, char* lds, int tid)
{
    const int w = tid >> 6, l = tid & 63;
    #pragma unroll
    for (int i = 0; i < 4; ++i) {
        int grp = i * 4 + w;                 // 8-row group 0..15
        int row = grp * 8 + (l >> 3);
        int srcb = ((l & 7) * 16) ^ ((l >> 3) << 4);
        const char* g = (const char*)(gbase + (size_t)row * NE) + srcb;
        char* d = lds + grp * 1024;          // wave-uniform base; HW adds lane*16
        __builtin_amdgcn_global_load_lds((gvoid_t*)g, (lvoid_t*)d, 16, 0, 0);
    }
}

// Stage a 64-row x 256B (128 bf16) tile (row stride 1024 bf16) into 16KB LDS,
// swizzled: lds[row*256 + (x ^ ((row&7)<<4))] = g[row][x].
__device__ __forceinline__ void stage64x256(const unsigned short* gbase, char* lds, int tid)
{
    const int w = tid >> 6, l = tid & 63;
    #pragma unroll
    for (int i = 0; i < 4; ++i) {
        int row0 = i * 16 + w * 4;
        int row = row0 + (l >> 4);
        int srcb = ((l & 15) * 16) ^ ((row & 7) << 4);
        const char* g = (const char*)(gbase + (size_t)row * 1024) + srcb;
        char* d = lds + row0 * 256;
        __builtin_amdgcn_global_load_lds((gvoid_t*)g, (lvoid_t*)d, 16, 0, 0);
    }
}

// f32 -> bf16 (RNE), 8 elems/thread.
__global__ __launch_bounds__(256)
void conv_bf16(const float* __restrict__ src, unsigned short* __restrict__ dst)
{
    size_t i = ((size_t)blockIdx.x * 256 + threadIdx.x) * 8;
    float4 a0 = *(const float4*)(src + i);
    float4 a1 = *(const float4*)(src + i + 4);
    uint4 p;
    p.x = f2b(a0.x) | ((unsigned)f2b(a0.y) << 16);
    p.y = f2b(a0.z) | ((unsigned)f2b(a0.w) << 16);
    p.z = f2b(a1.x) | ((unsigned)f2b(a1.y) << 16);
    p.w = f2b(a1.z) | ((unsigned)f2b(a1.w) << 16);
    *(uint4*)(dst + i) = p;
}

// C[M,N] = A[M,K] @ W[N,K]^T + bias; A,W bf16; M=8192, N=K=1024.
// grid 512 linear, XCD-swizzled. MODE 0: bf16 row-major. MODE 1: bf16 V^T. MODE 2: f32.
template<int MODE>
__global__ __launch_bounds__(256)
void proj_bt(const unsigned short* __restrict__ A, const unsigned short* __restrict__ W,
             const float* __restrict__ bias, void* __restrict__ outp)
{
    __shared__ char Asm[16384], Bsm[16384];
    const int tid  = threadIdx.x;
    const int lane = tid & 63;
    const int wid  = tid >> 6;
    const int wr = wid >> 1, wc = wid & 1;
    const int swz = (blockIdx.x & 7) * 64 + (blockIdx.x >> 3);
    const int rowbase = (swz >> 3) * 128;
    const int colbase = (swz & 7) * 128;
    f32x4 acc[4][4] = {};

    for (int kt = 0; kt < 16; ++kt) {
        __syncthreads();
        stage128(A + (size_t)rowbase * NE + kt * 64, Asm, tid);
        stage128(W + (size_t)colbase * NE + kt * 64, Bsm, tid);
        __syncthreads();
        #pragma unroll
        for (int ks = 0; ks < 2; ++ks) {
            const int kb = ks * 64 + (lane >> 4) * 16;
            bf16x8 af[4], bf[4];
            #pragma unroll
            for (int m = 0; m < 4; ++m) {
                int row = wr * 64 + m * 16 + (lane & 15);
                af[m] = *(const bf16x8*)(Asm + ((row * 128 + kb) ^ ((row & 7) << 4)));
            }
            #pragma unroll
            for (int n = 0; n < 4; ++n) {
                int row = wc * 64 + n * 16 + (lane & 15);
                bf[n] = *(const bf16x8*)(Bsm + ((row * 128 + kb) ^ ((row & 7) << 4)));
            }
            #pragma unroll
            for (int m = 0; m < 4; ++m)
                #pragma unroll
                for (int n = 0; n < 4; ++n)
                    acc[m][n] = __builtin_amdgcn_mfma_f32_16x16x32_bf16(af[m], bf[n], acc[m][n], 0, 0, 0);
        }
    }

    #pragma unroll
    for (int m = 0; m < 4; ++m) {
        #pragma unroll
        for (int n = 0; n < 4; ++n) {
            int col = colbase + wc * 64 + n * 16 + (lane & 15);
            float bv = bias[col];
            #pragma unroll
            for (int r = 0; r < 4; ++r) {
                int row = rowbase + wr * 64 + m * 16 + (lane >> 4) * 4 + r;
                float v = acc[m][n][r] + bv;
                if (MODE == 0) {
                    ((unsigned short*)outp)[(size_t)row * NE + col] = f2b(v);
                } else if (MODE == 1) {
                    int b = row >> 10, s = row & 1023, h = col >> 6, d = col & 63;
                    ((unsigned short*)outp)[((size_t)((b * 16 + h) * 64 + d) << 10) + s] = f2b(v);
                } else {
                    ((float*)outp)[(size_t)row * NE + col] = v;
                }
            }
        }
    }
}

// Fused attention. grid 1024 linear, XCD-swizzled (16 bh per XCD).
// Per block: 128 q-rows of one (b,h). Q fragments in registers; K staged+prefetched;
// V staged async per kt; normalization folded into exp2 exponent (lt[q]).
__global__ __launch_bounds__(256, 2)
void fused_attn(const unsigned short* __restrict__ Q,
                const unsigned short* __restrict__ K,
                const unsigned short* __restrict__ VT,
                float* __restrict__ attn, unsigned short* __restrict__ Og)
{
    __shared__ char Ksm[16384];
    __shared__ char Vsm[16384];
    __shared__ char Psm[32768];          // Q staged here initially; then P tiles
    __shared__ float rs4[4][128];
    __shared__ float lt[128];
    const int tid  = threadIdx.x;
    const int lane = tid & 63;
    const int w    = tid >> 6;
    const int swzb = (blockIdx.x & 7) * 128 + (blockIdx.x >> 3);
    const int bh = swzb >> 3, qt = swzb & 7;
    const int b = bh >> 4, h = bh & 15;
    const unsigned short* Qg = Q  + (size_t)(b * 1024 + qt * 128) * 1024 + h * 64;
    const unsigned short* Kg = K  + (size_t)(b * 1024) * 1024 + h * 64;
    const unsigned short* Vg = VT + (size_t)bh * 64 * 1024;

    // stage Q via Psm, hoist fragments to registers
    stage128(Qg, Psm, tid);
    __syncthreads();
    bf16x8 qf[2][8];
    #pragma unroll
    for (int ks = 0; ks < 2; ++ks) {
        const int kb = ks * 64 + (lane >> 4) * 16;
        #pragma unroll
        for (int n = 0; n < 8; ++n) {
            int row = n * 16 + (lane & 15);
            qf[ks][n] = *(const bf16x8*)(Psm + ((row * 128 + kb) ^ ((row & 7) << 4)));
        }
    }
    stage128(Kg, Ksm, tid);   // K(0)

    // ---- loop 1: row sums of exp2(s*C1 + C2) ----
    float rs_p[8] = {0.f, 0.f, 0.f, 0.f, 0.f, 0.f, 0.f, 0.f};
    for (int kt = 0; kt < 8; ++kt) {
        __syncthreads();                       // K(kt) ready
        f32x4 sa[2][8] = {};
        __builtin_amdgcn_s_setprio(1);
        #pragma unroll
        for (int ks = 0; ks < 2; ++ks) {
            const int kb = ks * 64 + (lane >> 4) * 16;
            bf16x8 kf[2];
            #pragma unroll
            for (int m = 0; m < 2; ++m) {
                int row = w * 32 + m * 16 + (lane & 15);
                kf[m] = *(const bf16x8*)(Ksm + ((row * 128 + kb) ^ ((row & 7) << 4)));
            }
            #pragma unroll
            for (int m = 0; m < 2; ++m)
                #pragma unroll
                for (int n = 0; n < 8; ++n)
                    sa[m][n] = __builtin_amdgcn_mfma_f32_16x16x32_bf16(kf[m], qf[ks][n], sa[m][n], 0, 0, 0);
        }
        __builtin_amdgcn_s_setprio(0);
        __syncthreads();                       // Ksm free
        if (kt < 7) stage128(Kg + (size_t)((kt + 1) * 128) * 1024, Ksm, tid);
        #pragma unroll
        for (int n = 0; n < 8; ++n)
            #pragma unroll
            for (int m = 0; m < 2; ++m)
                #pragma unroll
                for (int r = 0; r < 4; ++r)
                    rs_p[n] += exp2f(fmaf(sa[m][n][r], C1E, C2E));
    }
    #pragma unroll
    for (int n = 0; n < 8; ++n) {
        rs_p[n] += __shfl_xor(rs_p[n], 16);
        rs_p[n] += __shfl_xor(rs_p[n], 32);
    }
    if (lane < 16) {
        #pragma unroll
        for (int n = 0; n < 8; ++n) rs4[w][n * 16 + lane] = rs_p[n];
    }
    __syncthreads();
    if (tid < 128) {
        float l = rs4[0][tid] + rs4[1][tid] + rs4[2][tid] + rs4[3][tid];
        lt[tid] = C2E - __log2f(l);            // exp2(s*C1 + lt) = exp(s/8-8)/l
    }
    stage128(Kg, Ksm, tid);                    // K(0) for loop 2

    // ---- loop 2: normalized attn write + PV ----
    f32x4 oa[2][4] = {};
    float* attnq = attn + ((size_t)bh * 1024 + qt * 128) * 1024;
    for (int kt = 0; kt < 8; ++kt) {
        __syncthreads();                       // K(kt) ready; Vsm free; lt visible
        stage64x256(Vg + kt * 128, Vsm, tid);  // V(kt), drained by barrier B
        f32x4 sa[2][8] = {};
        __builtin_amdgcn_s_setprio(1);
        #pragma unroll
        for (int ks = 0; ks < 2; ++ks) {
            const int kb = ks * 64 + (lane >> 4) * 16;
            bf16x8 kf[2];
            #pragma unroll
            for (int m = 0; m < 2; ++m) {
                int row = w * 32 + m * 16 + (lane & 15);
                kf[m] = *(const bf16x8*)(Ksm + ((row * 128 + kb) ^ ((row & 7) << 4)));
            }
            #pragma unroll
            for (int m = 0; m < 2; ++m)
                #pragma unroll
                for (int n = 0; n < 8; ++n)
                    sa[m][n] = __builtin_amdgcn_mfma_f32_16x16x32_bf16(kf[m], qf[ks][n], sa[m][n], 0, 0, 0);
        }
        __builtin_amdgcn_s_setprio(0);
        // normalized P: attn f32 store + bf16 pack into Psm
        #pragma unroll
        for (int n = 0; n < 8; ++n) {
            int q = n * 16 + (lane & 15);
            float ltq = lt[q];
            #pragma unroll
            for (int m = 0; m < 2; ++m) {
                int k0 = w * 32 + m * 16 + (lane >> 4) * 4;
                float4 p4;
                p4.x = exp2f(fmaf(sa[m][n][0], C1E, ltq));
                p4.y = exp2f(fmaf(sa[m][n][1], C1E, ltq));
                p4.z = exp2f(fmaf(sa[m][n][2], C1E, ltq));
                p4.w = exp2f(fmaf(sa[m][n][3], C1E, ltq));
                *(float4*)(attnq + (size_t)q * 1024 + kt * 128 + k0) = p4;
                uint2 pk;
                pk.x = f2b(p4.x) | ((unsigned)f2b(p4.y) << 16);
                pk.y = f2b(p4.z) | ((unsigned)f2b(p4.w) << 16);
                *(uint2*)(Psm + ((q * 256 + k0 * 2) ^ ((q & 7) << 4))) = pk;
            }
        }
        __syncthreads();                       // B: Psm ready; V(kt) drained; Ksm free
        if (kt < 7) stage128(Kg + (size_t)((kt + 1) * 128) * 1024, Ksm, tid);
        __builtin_amdgcn_s_setprio(1);
        #pragma unroll
        for (int ks = 0; ks < 4; ++ks) {
            const int kb = ks * 64 + (lane >> 4) * 16;
            bf16x8 pa[2], vb[4];
            #pragma unroll
            for (int m2 = 0; m2 < 2; ++m2) {
                int row = w * 32 + m2 * 16 + (lane & 15);
                pa[m2] = *(const bf16x8*)(Psm + ((row * 256 + kb) ^ ((row & 7) << 4)));
            }
            #pragma unroll
            for (int n2 = 0; n2 < 4; ++n2) {
                int d = n2 * 16 + (lane & 15);
                vb[n2] = *(const bf16x8*)(Vsm + d * 256 + (kb ^ ((d & 7) << 4)));
            }
            #pragma unroll
            for (int m2 = 0; m2 < 2; ++m2)
                #pragma unroll
                for (int n2 = 0; n2 < 4; ++n2)
                    oa[m2][n2] = __builtin_amdgcn_mfma_f32_16x16x32_bf16(pa[m2], vb[n2], oa[m2][n2], 0, 0, 0);
        }
        __builtin_amdgcn_s_setprio(0);
    }
    unsigned short* Ob = Og + (size_t)(b * 1024 + qt * 128) * 1024 + h * 64;
    #pragma unroll
    for (int m2 = 0; m2 < 2; ++m2)
        #pragma unroll
        for (int n2 = 0; n2 < 4; ++n2) {
            int d = n2 * 16 + (lane & 15);
            #pragma unroll
            for (int r = 0; r < 4; ++r) {
                int qrow = w * 32 + m2 * 16 + (lane >> 4) * 4 + r;
                Ob[(size_t)qrow * 1024 + d] = f2b(oa[m2][n2][r]);
            }
        }
}

extern "C" void kernel_launch(void* const* d_in, const int* in_sizes, int n_in,
                              void* d_out, int out_size, void* d_ws, size_t ws_size,
                              hipStream_t stream) {
    (void)in_sizes; (void)n_in; (void)out_size; (void)ws_size;
    const float* q    = (const float*)d_in[0];
    const float* Wq_w = (const float*)d_in[1];
    const float* Wq_b = (const float*)d_in[2];
    const float* Wk_w = (const float*)d_in[3];
    const float* Wk_b = (const float*)d_in[4];
    const float* Wv_w = (const float*)d_in[5];
    const float* Wv_b = (const float*)d_in[6];
    const float* Wo_w = (const float*)d_in[7];
    const float* Wo_b = (const float*)d_in[8];

    char* ws = (char*)d_ws;                              // ws use: 48 MiB
    unsigned short* Qws  = (unsigned short*)(ws);        // Q bf16, later O bf16
    unsigned short* Kws  = (unsigned short*)(ws + (16u << 20));  // K bf16, later Wo bf16
    unsigned short* VTws = (unsigned short*)(ws + (32u << 20));

    float* outp  = (float*)d_out;                        // f32 out [8,1024,1024]
    float* attnp = outp + 8388608;                       // f32 attn [8,16,1024,1024]

    // bf16 scratch inside the attn region (free until fused_attn writes it)
    char* scr = (char*)attnp;
    unsigned short* qbf = (unsigned short*)scr;                    // 16 MiB
    unsigned short* wqb = (unsigned short*)(scr + (16u << 20));    // 2 MiB each
    unsigned short* wkb = (unsigned short*)(scr + (18u << 20));
    unsigned short* wvb = (unsigned short*)(scr + (20u << 20));

    dim3 blk(256);
    conv_bf16<<<dim3(4096), blk, 0, stream>>>(q, qbf);
    conv_bf16<<<dim3(512),  blk, 0, stream>>>(Wq_w, wqb);
    conv_bf16<<<dim3(512),  blk, 0, stream>>>(Wk_w, wkb);
    conv_bf16<<<dim3(512),  blk, 0, stream>>>(Wv_w, wvb);
    proj_bt<0><<<dim3(512), blk, 0, stream>>>(qbf, wqb, Wq_b, Qws);
    proj_bt<0><<<dim3(512), blk, 0, stream>>>(qbf, wkb, Wk_b, Kws);
    proj_bt<1><<<dim3(512), blk, 0, stream>>>(qbf, wvb, Wv_b, VTws);
    fused_attn<<<dim3(1024), blk, 0, stream>>>(Qws, Kws, VTws, attnp, Qws);
    conv_bf16<<<dim3(512),  blk, 0, stream>>>(Wo_w, Kws);          // Kws free now
    proj_bt<2><<<dim3(512), blk, 0, stream>>>(Qws, Kws, Wo_b, outp);
}